// Round 1
// baseline (152.379 us; speedup 1.0000x reference)
//
#include <hip/hip_runtime.h>
#include <stdint.h>

typedef unsigned short u16;
using bf16x8 = __attribute__((ext_vector_type(8))) short;
using f32x4  = __attribute__((ext_vector_type(4))) float;

#define EPS_GN 1e-5f

__device__ __forceinline__ u16 f2bf(float f) {
  union { float f; uint32_t u; } x; x.f = f;
  uint32_t r = x.u + 0x7FFFu + ((x.u >> 16) & 1u);
  return (u16)(r >> 16);
}

__device__ __forceinline__ void gload_lds16(const void* g, void* l) {
  __builtin_amdgcn_global_load_lds(
      (const __attribute__((address_space(1))) unsigned int*)g,
      (__attribute__((address_space(3))) unsigned int*)l, 16, 0, 0);
}

// ---------------- GroupNorm ----------------
// grid 512: each block reduces 8192 contiguous floats of one (b,g) segment.
__global__ __launch_bounds__(256) void gn_partial(const float* __restrict__ x,
                                                  float* __restrict__ part) {
  int bg = blockIdx.x >> 3, seg = blockIdx.x & 7;
  const float4* base = (const float4*)(x + (size_t)bg * 65536 + (size_t)seg * 8192);
  float s = 0.f, s2 = 0.f;
  for (int i = threadIdx.x; i < 2048; i += 256) {
    float4 v = base[i];
    s  += v.x + v.y + v.z + v.w;
    s2 += v.x*v.x + v.y*v.y + v.z*v.z + v.w*v.w;
  }
  for (int m = 1; m < 64; m <<= 1) { s += __shfl_xor(s, m); s2 += __shfl_xor(s2, m); }
  __shared__ float red[4][2];
  int wave = threadIdx.x >> 6;
  if ((threadIdx.x & 63) == 0) { red[wave][0] = s; red[wave][1] = s2; }
  __syncthreads();
  if (threadIdx.x == 0) {
    float a = 0.f, b = 0.f;
    for (int w = 0; w < 4; ++w) { a += red[w][0]; b += red[w][1]; }
    part[blockIdx.x * 2] = a; part[blockIdx.x * 2 + 1] = b;
  }
}

__global__ void gn_finish(const float* __restrict__ part, float* __restrict__ stats) {
  int bg = threadIdx.x;  // 64 threads
  float s = 0.f, s2 = 0.f;
  for (int i = 0; i < 8; ++i) { s += part[(bg*8+i)*2]; s2 += part[(bg*8+i)*2 + 1]; }
  float mean = s * (1.f/65536.f);
  float var  = s2 * (1.f/65536.f) - mean*mean;
  stats[bg*2]   = mean;
  stats[bg*2+1] = rsqrtf(var + EPS_GN);
}

// normalize + transpose [B,C,S] -> xn bf16 [B,S,C]
__global__ __launch_bounds__(256) void gn_apply(const float* __restrict__ x,
    const float* __restrict__ stats, const float* __restrict__ w,
    const float* __restrict__ bb, u16* __restrict__ xn) {
  __shared__ float t[32][33];
  int s0 = blockIdx.x * 32, c0 = blockIdx.y * 32, b = blockIdx.z;
  for (int i = 0; i < 4; ++i) {
    int c = c0 + threadIdx.y + i * 8;
    int g = c >> 6;
    float mean = stats[(b*8+g)*2], rstd = stats[(b*8+g)*2+1];
    float v = x[((size_t)b*512 + c)*1024 + s0 + threadIdx.x];
    t[threadIdx.y + i*8][threadIdx.x] = (v - mean) * rstd * w[c] + bb[c];
  }
  __syncthreads();
  for (int i = 0; i < 4; ++i) {
    int s = s0 + threadIdx.y + i * 8;
    xn[((size_t)b*1024 + s)*512 + c0 + threadIdx.x] = f2bf(t[threadIdx.x][threadIdx.y + i*8]);
  }
}

// ---------------- weight fp32 -> bf16 ----------------
__global__ __launch_bounds__(256) void cvt_w4(
    const float4* __restrict__ w0, const float4* __restrict__ w1,
    const float4* __restrict__ w2, const float4* __restrict__ w3,
    u16* __restrict__ o0, u16* __restrict__ o1,
    u16* __restrict__ o2, u16* __restrict__ o3) {
  int i = blockIdx.x * 256 + threadIdx.x;      // 262144 threads, 4 segs x 65536 float4
  int seg = i >> 16, j = i & 65535;
  const float4* w = (seg == 0) ? w0 : (seg == 1) ? w1 : (seg == 2) ? w2 : w3;
  u16* o = (seg == 0) ? o0 : (seg == 1) ? o1 : (seg == 2) ? o2 : o3;
  float4 v = w[j];
  o[j*4+0] = f2bf(v.x); o[j*4+1] = f2bf(v.y); o[j*4+2] = f2bf(v.z); o[j*4+3] = f2bf(v.w);
}

// ---------------- GEMM (normal): Out[m][n] = X[m][:]·W[n][:] + bias[n], bf16 out ----------------
// 128x128 tile, BK=64, both-sides XOR swizzle on LDS tiles.
__global__ __launch_bounds__(256) void gemm_nt(const u16* __restrict__ X,
    const u16* __restrict__ W, const float* __restrict__ bias,
    u16* __restrict__ Out, int M, int N, int K) {
  __shared__ __align__(16) u16 As[128*64];
  __shared__ __align__(16) u16 Bs[128*64];
  int m0 = blockIdx.x * 128, n0 = blockIdx.y * 128;
  int t = threadIdx.x, lane = t & 63, wave = t >> 6;
  int wm = wave >> 1, wn = wave & 1;
  int lr = lane & 15, lg = lane >> 4;
  f32x4 acc[4][4] = {};
  for (int k0 = 0; k0 < K; k0 += 64) {
    __syncthreads();
    for (int c = 0; c < 4; ++c) {
      int chunk = wave * 4 + c;           // 16 chunks x 1KB per tile
      int e = chunk * 512 + lane * 8;
      int r = e >> 6, col = e & 63;
      int scol = col ^ ((r & 7) << 3);    // pre-swizzled source (rule #21)
      gload_lds16(X + (size_t)(m0 + r) * K + k0 + scol, (char*)As + chunk * 1024);
      gload_lds16(W + (size_t)(n0 + r) * K + k0 + scol, (char*)Bs + chunk * 1024);
    }
    __syncthreads();
    bf16x8 af[4][2], bfr[4][2];
    for (int i = 0; i < 4; ++i)
      for (int kk = 0; kk < 2; ++kk) {
        int ra = wm * 64 + i * 16 + lr;
        int ca = (kk * 32 + lg * 8) * 2;
        af[i][kk]  = *(const bf16x8*)((const char*)As + ((ra * 128 + ca) ^ ((ra & 7) << 4)));
        int rb = wn * 64 + i * 16 + lr;
        bfr[i][kk] = *(const bf16x8*)((const char*)Bs + ((rb * 128 + ca) ^ ((rb & 7) << 4)));
      }
    for (int kk = 0; kk < 2; ++kk)
      for (int i = 0; i < 4; ++i)
        for (int j = 0; j < 4; ++j)
          acc[i][j] = __builtin_amdgcn_mfma_f32_16x16x32_bf16(af[i][kk], bfr[j][kk], acc[i][j], 0, 0, 0);
  }
  for (int i = 0; i < 4; ++i)
    for (int j = 0; j < 4; ++j) {
      int col = n0 + wn * 64 + j * 16 + lr;
      float bv = bias[col];
      int rowb = m0 + wm * 64 + i * 16 + lg * 4;
      for (int r = 0; r < 4; ++r)
        Out[(size_t)(rowb + r) * N + col] = f2bf(acc[i][j][r] + bv);
    }
}

// ---------------- GEMM (swapped): C^T[n][m] = W[n][:]·X[m][:] + bias[n] ----------------
// mode 0: bf16 out flat [Nf][M]   (used for V -> vT)
// mode 1: fp32 out [B][C][S] with bias + residual (final projection)
__global__ __launch_bounds__(256) void gemm_tn(const u16* __restrict__ Wt,
    const u16* __restrict__ X, const float* __restrict__ bias,
    const float* __restrict__ resid, void* __restrict__ Out,
    int M, int Nf, int K, int mode) {
  __shared__ __align__(16) u16 As[128*64];
  __shared__ __align__(16) u16 Bs[128*64];
  int m0 = blockIdx.x * 128, n0 = blockIdx.y * 128;
  int t = threadIdx.x, lane = t & 63, wave = t >> 6;
  int wm = wave >> 1, wn = wave & 1;
  int lr = lane & 15, lg = lane >> 4;
  f32x4 acc[4][4] = {};
  for (int k0 = 0; k0 < K; k0 += 64) {
    __syncthreads();
    for (int c = 0; c < 4; ++c) {
      int chunk = wave * 4 + c;
      int e = chunk * 512 + lane * 8;
      int r = e >> 6, col = e & 63;
      int scol = col ^ ((r & 7) << 3);
      gload_lds16(Wt + (size_t)(n0 + r) * K + k0 + scol, (char*)As + chunk * 1024);
      gload_lds16(X  + (size_t)(m0 + r) * K + k0 + scol, (char*)Bs + chunk * 1024);
    }
    __syncthreads();
    bf16x8 af[4][2], bfr[4][2];
    for (int i = 0; i < 4; ++i)
      for (int kk = 0; kk < 2; ++kk) {
        int ra = wm * 64 + i * 16 + lr;
        int ca = (kk * 32 + lg * 8) * 2;
        af[i][kk]  = *(const bf16x8*)((const char*)As + ((ra * 128 + ca) ^ ((ra & 7) << 4)));
        int rb = wn * 64 + i * 16 + lr;
        bfr[i][kk] = *(const bf16x8*)((const char*)Bs + ((rb * 128 + ca) ^ ((rb & 7) << 4)));
      }
    for (int kk = 0; kk < 2; ++kk)
      for (int i = 0; i < 4; ++i)
        for (int j = 0; j < 4; ++j)
          acc[i][j] = __builtin_amdgcn_mfma_f32_16x16x32_bf16(af[i][kk], bfr[j][kk], acc[i][j], 0, 0, 0);
  }
  for (int i = 0; i < 4; ++i)
    for (int j = 0; j < 4; ++j) {
      int mcol = m0 + wn * 64 + j * 16 + lr;
      for (int r = 0; r < 4; ++r) {
        int nrow = n0 + wm * 64 + i * 16 + lg * 4 + r;
        float v = acc[i][j][r] + bias[nrow];
        if (mode == 0) {
          ((u16*)Out)[(size_t)nrow * M + mcol] = f2bf(v);
        } else {
          size_t b = (size_t)(mcol >> 10); int s = mcol & 1023;
          size_t addr = (b * 512 + nrow) * 1024 + s;
          ((float*)Out)[addr] = v + resid[addr];
        }
      }
    }
}

// ---------------- flash attention ----------------
// grid (16 q-blocks, 64 b*h); 4 waves, 16 q-rows per wave; KV tiles of 64.
__global__ __launch_bounds__(256) void attn_fwd(const u16* __restrict__ q,
    const u16* __restrict__ k, const u16* __restrict__ vT, u16* __restrict__ o) {
  __shared__ __align__(16) u16 Ks[64*64];        // [kv][d]   swizzled
  __shared__ __align__(16) u16 Vt[64*64];        // [d][kv]   swizzled
  __shared__ __align__(16) u16 Ps[4][16*72];     // per-wave P [16][72] (padded)
  int qb = blockIdx.x, bh = blockIdx.y;
  int b = bh >> 3, h = bh & 7;
  int t = threadIdx.x, lane = t & 63, wave = t >> 6;
  int lr = lane & 15, lg = lane >> 4;
  int qrow0 = qb * 64 + wave * 16;
  const u16* qp = q + (size_t)(b * 1024 + qrow0 + lr) * 512 + h * 64 + lg * 8;
  bf16x8 qf0 = *(const bf16x8*)qp;
  bf16x8 qf1 = *(const bf16x8*)(qp + 32);
  float mi[4] = {-1e30f, -1e30f, -1e30f, -1e30f};
  float li[4] = {0.f, 0.f, 0.f, 0.f};
  f32x4 oacc[4] = {};
  const float scale = 0.125f;
  for (int kv = 0; kv < 1024; kv += 64) {
    __syncthreads();
    for (int c = 0; c < 2; ++c) {
      int chunk = wave * 2 + c;           // 8 chunks x 1KB per tile
      int e = chunk * 512 + lane * 8;
      int r = e >> 6, col = e & 63;
      int scol = col ^ ((r & 7) << 3);
      gload_lds16(k  + (size_t)(b * 1024 + kv + r) * 512 + h * 64 + scol, (char*)Ks + chunk * 1024);
      gload_lds16(vT + (size_t)(h * 64 + r) * 8192 + b * 1024 + kv + scol, (char*)Vt + chunk * 1024);
    }
    __syncthreads();
    f32x4 sa[4];
    for (int n = 0; n < 4; ++n) {
      int rk = n * 16 + lr;
      bf16x8 kf0 = *(const bf16x8*)((const char*)Ks + ((rk * 128 + lg * 16)       ^ ((rk & 7) << 4)));
      bf16x8 kf1 = *(const bf16x8*)((const char*)Ks + ((rk * 128 + 64 + lg * 16)  ^ ((rk & 7) << 4)));
      f32x4 z = {};
      z = __builtin_amdgcn_mfma_f32_16x16x32_bf16(qf0, kf0, z, 0, 0, 0);
      z = __builtin_amdgcn_mfma_f32_16x16x32_bf16(qf1, kf1, z, 0, 0, 0);
      sa[n] = z;
    }
    u16* P = Ps[wave];
    for (int r = 0; r < 4; ++r) {
      float s0 = sa[0][r]*scale, s1 = sa[1][r]*scale, s2 = sa[2][r]*scale, s3 = sa[3][r]*scale;
      float mx = fmaxf(fmaxf(s0, s1), fmaxf(s2, s3));
      for (int msk = 1; msk < 16; msk <<= 1) mx = fmaxf(mx, __shfl_xor(mx, msk));
      float nm = fmaxf(mi[r], mx);
      float al = __expf(mi[r] - nm);
      float p0 = __expf(s0 - nm), p1 = __expf(s1 - nm), p2 = __expf(s2 - nm), p3 = __expf(s3 - nm);
      float rs = p0 + p1 + p2 + p3;
      for (int msk = 1; msk < 16; msk <<= 1) rs += __shfl_xor(rs, msk);
      mi[r] = nm;
      li[r] = li[r] * al + rs;
      for (int n = 0; n < 4; ++n) oacc[n][r] *= al;
      int prow = lg * 4 + r;
      P[prow*72 +      lr] = f2bf(p0);
      P[prow*72 + 16 + lr] = f2bf(p1);
      P[prow*72 + 32 + lr] = f2bf(p2);
      P[prow*72 + 48 + lr] = f2bf(p3);
    }
    bf16x8 pf0 = *(const bf16x8*)&P[lr*72 + lg*8];
    bf16x8 pf1 = *(const bf16x8*)&P[lr*72 + 32 + lg*8];
    for (int n = 0; n < 4; ++n) {
      int rv = n * 16 + lr;
      bf16x8 vf0 = *(const bf16x8*)((const char*)Vt + ((rv * 128 + lg * 16)      ^ ((rv & 7) << 4)));
      bf16x8 vf1 = *(const bf16x8*)((const char*)Vt + ((rv * 128 + 64 + lg * 16) ^ ((rv & 7) << 4)));
      oacc[n] = __builtin_amdgcn_mfma_f32_16x16x32_bf16(pf0, vf0, oacc[n], 0, 0, 0);
      oacc[n] = __builtin_amdgcn_mfma_f32_16x16x32_bf16(pf1, vf1, oacc[n], 0, 0, 0);
    }
  }
  for (int n = 0; n < 4; ++n) {
    int col = h * 64 + n * 16 + lr;
    for (int r = 0; r < 4; ++r) {
      int row = qrow0 + lg * 4 + r;
      o[(size_t)(b * 1024 + row) * 512 + col] = f2bf(oacc[n][r] / li[r]);
    }
  }
}

extern "C" void kernel_launch(void* const* d_in, const int* in_sizes, int n_in,
                              void* d_out, int out_size, void* d_ws, size_t ws_size,
                              hipStream_t stream) {
  const float* x    = (const float*)d_in[0];
  const float* gn_w = (const float*)d_in[1];
  const float* gn_b = (const float*)d_in[2];
  const float* wq   = (const float*)d_in[3];
  const float* bq   = (const float*)d_in[4];
  const float* wk   = (const float*)d_in[5];
  const float* bk   = (const float*)d_in[6];
  const float* wv   = (const float*)d_in[7];
  const float* bv   = (const float*)d_in[8];
  const float* wp   = (const float*)d_in[9];
  const float* bp   = (const float*)d_in[10];

  char* ws = (char*)d_ws;
  float* stats = (float*)ws;                       // 512 B
  float* part  = (float*)(ws + 512);               // 4 KB
  u16* wqb = (u16*)(ws + 8192);                    // 4 x 512 KB
  u16* wkb = wqb + 262144;
  u16* wvb = wkb + 262144;
  u16* wpb = wvb + 262144;
  u16* xn  = (u16*)(ws + 2105344);                 // 8 MB each below
  u16* qb  = xn + 4194304;
  u16* kb  = qb + 4194304;
  u16* vTb = kb + 4194304;
  u16* attno = xn;                                 // alias: xn dead after QKV GEMMs

  gn_partial<<<512, 256, 0, stream>>>(x, part);
  gn_finish<<<1, 64, 0, stream>>>(part, stats);
  gn_apply<<<dim3(32, 16, 8), dim3(32, 8), 0, stream>>>(x, stats, gn_w, gn_b, xn);
  cvt_w4<<<1024, 256, 0, stream>>>((const float4*)wq, (const float4*)wk,
                                   (const float4*)wv, (const float4*)wp,
                                   wqb, wkb, wvb, wpb);
  gemm_nt<<<dim3(64, 4), 256, 0, stream>>>(xn, wqb, bq, qb, 8192, 512, 512);
  gemm_nt<<<dim3(64, 4), 256, 0, stream>>>(xn, wkb, bk, kb, 8192, 512, 512);
  gemm_tn<<<dim3(64, 4), 256, 0, stream>>>(wvb, xn, bv, nullptr, vTb, 8192, 512, 512, 0);
  attn_fwd<<<dim3(16, 64), 256, 0, stream>>>(qb, kb, vTb, attno);
  gemm_tn<<<dim3(64, 4), 256, 0, stream>>>(wpb, attno, bp, x, d_out, 8192, 512, 512, 1);
}

// Round 2
// 115.329 us; speedup vs baseline: 1.3213x; 1.3213x over previous
//
#include <hip/hip_runtime.h>
#include <stdint.h>

typedef unsigned short u16;
using bf16x8 = __attribute__((ext_vector_type(8))) short;
using f32x4  = __attribute__((ext_vector_type(4))) float;
using f32x16 = __attribute__((ext_vector_type(16))) float;

#define EPS_GN 1e-5f
#define SCL 0.18033688011112042f   // 0.125 * log2(e)

__device__ __forceinline__ u16 f2bf(float f) {
  union { float f; uint32_t u; } x; x.f = f;
  uint32_t r = x.u + 0x7FFFu + ((x.u >> 16) & 1u);
  return (u16)(r >> 16);
}

__device__ __forceinline__ void gload_lds16(const void* g, void* l) {
  __builtin_amdgcn_global_load_lds(
      (const __attribute__((address_space(1))) unsigned int*)g,
      (__attribute__((address_space(3))) unsigned int*)l, 16, 0, 0);
}

// ---------------- GroupNorm ----------------
__global__ __launch_bounds__(256) void gn_partial(const float* __restrict__ x,
                                                  float* __restrict__ part) {
  int bg = blockIdx.x >> 3, seg = blockIdx.x & 7;
  const float4* base = (const float4*)(x + (size_t)bg * 65536 + (size_t)seg * 8192);
  float s = 0.f, s2 = 0.f;
  for (int i = threadIdx.x; i < 2048; i += 256) {
    float4 v = base[i];
    s  += v.x + v.y + v.z + v.w;
    s2 += v.x*v.x + v.y*v.y + v.z*v.z + v.w*v.w;
  }
  for (int m = 1; m < 64; m <<= 1) { s += __shfl_xor(s, m); s2 += __shfl_xor(s2, m); }
  __shared__ float red[4][2];
  int wave = threadIdx.x >> 6;
  if ((threadIdx.x & 63) == 0) { red[wave][0] = s; red[wave][1] = s2; }
  __syncthreads();
  if (threadIdx.x == 0) {
    float a = 0.f, b = 0.f;
    for (int w = 0; w < 4; ++w) { a += red[w][0]; b += red[w][1]; }
    part[blockIdx.x * 2] = a; part[blockIdx.x * 2 + 1] = b;
  }
}

__global__ void gn_finish(const float* __restrict__ part, float* __restrict__ stats) {
  int bg = threadIdx.x;  // 64 threads
  float s = 0.f, s2 = 0.f;
  for (int i = 0; i < 8; ++i) { s += part[(bg*8+i)*2]; s2 += part[(bg*8+i)*2 + 1]; }
  float mean = s * (1.f/65536.f);
  float var  = s2 * (1.f/65536.f) - mean*mean;
  stats[bg*2]   = mean;
  stats[bg*2+1] = rsqrtf(var + EPS_GN);
}

// normalize + transpose [B,C,S] -> xn bf16 [B,S,C]
__global__ __launch_bounds__(256) void gn_apply(const float* __restrict__ x,
    const float* __restrict__ stats, const float* __restrict__ w,
    const float* __restrict__ bb, u16* __restrict__ xn) {
  __shared__ float t[32][33];
  int s0 = blockIdx.x * 32, c0 = blockIdx.y * 32, b = blockIdx.z;
  for (int i = 0; i < 4; ++i) {
    int c = c0 + threadIdx.y + i * 8;
    int g = c >> 6;
    float mean = stats[(b*8+g)*2], rstd = stats[(b*8+g)*2+1];
    float v = x[((size_t)b*512 + c)*1024 + s0 + threadIdx.x];
    t[threadIdx.y + i*8][threadIdx.x] = (v - mean) * rstd * w[c] + bb[c];
  }
  __syncthreads();
  for (int i = 0; i < 4; ++i) {
    int s = s0 + threadIdx.y + i * 8;
    xn[((size_t)b*1024 + s)*512 + c0 + threadIdx.x] = f2bf(t[threadIdx.x][threadIdx.y + i*8]);
  }
}

// ---------------- weights fp32->bf16 (+ scale fold on wq, bias concat) ----------------
__global__ __launch_bounds__(256) void cvt_w(const float4* __restrict__ wq,
    const float4* __restrict__ wk, const float4* __restrict__ wv,
    const float4* __restrict__ wp, const float* __restrict__ bq,
    const float* __restrict__ bk, u16* __restrict__ wqkb, u16* __restrict__ wvb,
    u16* __restrict__ wpb, float* __restrict__ bqk) {
  int i = blockIdx.x * 256 + threadIdx.x;      // 262144 threads
  int seg = i >> 16, j = i & 65535;
  const float4* w = (seg == 0) ? wq : (seg == 1) ? wk : (seg == 2) ? wv : wp;
  u16* o = (seg == 0) ? wqkb : (seg == 1) ? (wqkb + 262144) : (seg == 2) ? wvb : wpb;
  float sc = (seg == 0) ? SCL : 1.f;
  float4 v = w[j];
  o[j*4+0] = f2bf(v.x*sc); o[j*4+1] = f2bf(v.y*sc);
  o[j*4+2] = f2bf(v.z*sc); o[j*4+3] = f2bf(v.w*sc);
  if (i < 1024) bqk[i] = (i < 512) ? bq[i]*SCL : bk[i-512];
}

// ---------------- GEMM (normal): Out[m][n] = X[m][:]·W[n][:] + bias[n], bf16 out ----------------
__global__ __launch_bounds__(256) void gemm_nt(const u16* __restrict__ X,
    const u16* __restrict__ W, const float* __restrict__ bias,
    u16* __restrict__ Out, int M, int N, int K) {
  __shared__ __align__(16) u16 As[128*64];
  __shared__ __align__(16) u16 Bs[128*64];
  int m0 = blockIdx.x * 128, n0 = blockIdx.y * 128;
  int t = threadIdx.x, lane = t & 63, wave = t >> 6;
  int wm = wave >> 1, wn = wave & 1;
  int lr = lane & 15, lg = lane >> 4;
  f32x4 acc[4][4] = {};
  for (int k0 = 0; k0 < K; k0 += 64) {
    __syncthreads();
    for (int c = 0; c < 4; ++c) {
      int chunk = wave * 4 + c;
      int e = chunk * 512 + lane * 8;
      int r = e >> 6, col = e & 63;
      int scol = col ^ ((r & 7) << 3);
      gload_lds16(X + (size_t)(m0 + r) * K + k0 + scol, (char*)As + chunk * 1024);
      gload_lds16(W + (size_t)(n0 + r) * K + k0 + scol, (char*)Bs + chunk * 1024);
    }
    __syncthreads();
    bf16x8 af[4][2], bfr[4][2];
    for (int i = 0; i < 4; ++i)
      for (int kk = 0; kk < 2; ++kk) {
        int ra = wm * 64 + i * 16 + lr;
        int ca = kk * 64 + lg * 16;
        af[i][kk]  = *(const bf16x8*)((const char*)As + ((ra * 128 + ca) ^ ((ra & 7) << 4)));
        int rb = wn * 64 + i * 16 + lr;
        bfr[i][kk] = *(const bf16x8*)((const char*)Bs + ((rb * 128 + ca) ^ ((rb & 7) << 4)));
      }
    for (int kk = 0; kk < 2; ++kk)
      for (int i = 0; i < 4; ++i)
        for (int j = 0; j < 4; ++j)
          acc[i][j] = __builtin_amdgcn_mfma_f32_16x16x32_bf16(af[i][kk], bfr[j][kk], acc[i][j], 0, 0, 0);
  }
  for (int i = 0; i < 4; ++i)
    for (int j = 0; j < 4; ++j) {
      int col = n0 + wn * 64 + j * 16 + lr;
      float bv = bias[col];
      int rowb = m0 + wm * 64 + i * 16 + lg * 4;
      for (int r = 0; r < 4; ++r)
        Out[(size_t)(rowb + r) * N + col] = f2bf(acc[i][j][r] + bv);
    }
}

// ---------------- GEMM (swapped): C^T[n][m] = W[n][:]·X[m][:] + bias[n] ----------------
// 128(n) x 64(m) tiles -> grid (M/64, N/128). mode 0: bf16 [N][M]; mode 1: fp32 [B][C][S] + resid.
__global__ __launch_bounds__(256) void gemm_tn2(const u16* __restrict__ Wt,
    const u16* __restrict__ X, const float* __restrict__ bias,
    const float* __restrict__ resid, void* __restrict__ Out,
    int M, int K, int mode) {
  __shared__ __align__(16) u16 As[128*64];
  __shared__ __align__(16) u16 Bs[64*64];
  int m0 = blockIdx.x * 64, n0 = blockIdx.y * 128;
  int t = threadIdx.x, lane = t & 63, wave = t >> 6;
  int wm = wave >> 1, wn = wave & 1;
  int lr = lane & 15, lg = lane >> 4;
  f32x4 acc[4][2] = {};
  for (int k0 = 0; k0 < K; k0 += 64) {
    __syncthreads();
    for (int c = 0; c < 4; ++c) {
      int chunk = wave * 4 + c;
      int e = chunk * 512 + lane * 8;
      int r = e >> 6, col = e & 63;
      int scol = col ^ ((r & 7) << 3);
      gload_lds16(Wt + (size_t)(n0 + r) * K + k0 + scol, (char*)As + chunk * 1024);
    }
    for (int c = 0; c < 2; ++c) {
      int chunk = wave * 2 + c;
      int e = chunk * 512 + lane * 8;
      int r = e >> 6, col = e & 63;
      int scol = col ^ ((r & 7) << 3);
      gload_lds16(X + (size_t)(m0 + r) * K + k0 + scol, (char*)Bs + chunk * 1024);
    }
    __syncthreads();
    bf16x8 af[4][2], bfr[2][2];
    for (int kk = 0; kk < 2; ++kk) {
      int ca = kk * 64 + lg * 16;
      for (int i = 0; i < 4; ++i) {
        int ra = wm * 64 + i * 16 + lr;
        af[i][kk] = *(const bf16x8*)((const char*)As + ((ra * 128 + ca) ^ ((ra & 7) << 4)));
      }
      for (int j = 0; j < 2; ++j) {
        int rb = wn * 32 + j * 16 + lr;
        bfr[j][kk] = *(const bf16x8*)((const char*)Bs + ((rb * 128 + ca) ^ ((rb & 7) << 4)));
      }
    }
    for (int kk = 0; kk < 2; ++kk)
      for (int i = 0; i < 4; ++i)
        for (int j = 0; j < 2; ++j)
          acc[i][j] = __builtin_amdgcn_mfma_f32_16x16x32_bf16(af[i][kk], bfr[j][kk], acc[i][j], 0, 0, 0);
  }
  for (int i = 0; i < 4; ++i)
    for (int j = 0; j < 2; ++j) {
      int mcol = m0 + wn * 32 + j * 16 + lr;
      for (int r = 0; r < 4; ++r) {
        int nrow = n0 + wm * 64 + i * 16 + lg * 4 + r;
        float v = acc[i][j][r] + bias[nrow];
        if (mode == 0) {
          ((u16*)Out)[(size_t)nrow * M + mcol] = f2bf(v);
        } else {
          size_t b = (size_t)(mcol >> 10); int s = mcol & 1023;
          size_t addr = (b * 512 + nrow) * 1024 + s;
          ((float*)Out)[addr] = v + resid[addr];
        }
      }
    }
}

// ---------------- flash attention, swapped 32x32 ----------------
// grid (8 q-blocks of 128, 64 b*h); 4 waves x 32 q-rows; KV tiles of 64.
// qk layout: [B*S][1024] (q cols 0..511 pre-scaled by SCL, k cols 512..1023)
__global__ __launch_bounds__(256) void attn_fwd(const u16* __restrict__ qk,
    const u16* __restrict__ vT, u16* __restrict__ o) {
  __shared__ __align__(16) u16 smem[8192];       // Ks 8KB | Vt 8KB; reused for epilogue
  u16* Ks = smem;
  u16* Vt = smem + 4096;
  int qb = blockIdx.x, bh = blockIdx.y;
  int b = bh >> 3, h = bh & 7;
  int t = threadIdx.x, lane = t & 63, wave = t >> 6;
  int lq = lane & 31, hi = lane >> 5;
  int qrow0 = qb * 128 + wave * 32;
  // Q fragment (B-operand): Q[qrow0+lq][s*16 + hi*8 + i]
  const u16* qp = qk + (size_t)(b * 1024 + qrow0 + lq) * 1024 + h * 64 + hi * 8;
  bf16x8 qf[4];
#pragma unroll
  for (int s = 0; s < 4; ++s) qf[s] = *(const bf16x8*)(qp + s * 16);
  float mi = -1e30f, li = 0.f;
  f32x16 ot[2] = {};
  for (int kv = 0; kv < 1024; kv += 64) {
    __syncthreads();
    for (int c = 0; c < 2; ++c) {
      int chunk = wave * 2 + c;
      int e = chunk * 512 + lane * 8;
      int r = e >> 6, col = e & 63;
      int scol = col ^ ((r & 7) << 3);
      gload_lds16(qk + (size_t)(b * 1024 + kv + r) * 1024 + 512 + h * 64 + scol,
                  (char*)Ks + chunk * 1024);
      gload_lds16(vT + (size_t)(h * 64 + r) * 8192 + b * 1024 + kv + scol,
                  (char*)Vt + chunk * 1024);
    }
    __syncthreads();
    // S^T tiles: st[n2] = K[n2*32..+31][:] · Q^T   (D: col=q, rows=kv)
    f32x16 st[2];
#pragma unroll
    for (int n2 = 0; n2 < 2; ++n2) {
      int rk = n2 * 32 + lq;
      f32x16 z = {};
#pragma unroll
      for (int s = 0; s < 4; ++s) {
        bf16x8 kf = *(const bf16x8*)((const char*)Ks +
                       ((rk * 128 + s * 32 + hi * 16) ^ ((rk & 7) << 4)));
        z = __builtin_amdgcn_mfma_f32_32x32x16_bf16(kf, qf[s], z, 0, 0, 0);
      }
      st[n2] = z;
    }
    // online softmax (log2 units; scale*log2e folded into Q)
    float a[16];
#pragma unroll
    for (int r = 0; r < 16; ++r) a[r] = fmaxf(st[0][r], st[1][r]);
#pragma unroll
    for (int s = 8; s > 0; s >>= 1)
#pragma unroll
      for (int r = 0; r < s; ++r) a[r] = fmaxf(a[r], a[r + s]);
    float mx = fmaxf(a[0], __shfl_xor(a[0], 32));
    if (!__all(mx <= mi + 10.f)) {     // defer-max (T13)
      float nm = fmaxf(mi, mx);
      float al = exp2f(mi - nm);
      li *= al;
#pragma unroll
      for (int r = 0; r < 16; ++r) { ot[0][r] *= al; ot[1][r] *= al; }
      mi = nm;
    }
    float sm[16];
#pragma unroll
    for (int r = 0; r < 16; ++r) {
      float e0 = exp2f(st[0][r] - mi);
      float e1 = exp2f(st[1][r] - mi);
      st[0][r] = e0; st[1][r] = e1;
      sm[r] = e0 + e1;
    }
#pragma unroll
    for (int s = 8; s > 0; s >>= 1)
#pragma unroll
      for (int r = 0; r < s; ++r) sm[r] += sm[r + s];
    li += sm[0] + __shfl_xor(sm[0], 32);
    // PV: ot[dt] += V^T · P  (P fragments built in-register)
#pragma unroll
    for (int n2 = 0; n2 < 2; ++n2) {
#pragma unroll
      for (int c = 0; c < 2; ++c) {
        int cg = n2 * 2 + c;
        int W0, W1, W2, W3;
        asm("v_cvt_pk_bf16_f32 %0, %1, %2" : "=v"(W0) : "v"(st[n2][8*c+0]), "v"(st[n2][8*c+1]));
        asm("v_cvt_pk_bf16_f32 %0, %1, %2" : "=v"(W1) : "v"(st[n2][8*c+2]), "v"(st[n2][8*c+3]));
        asm("v_cvt_pk_bf16_f32 %0, %1, %2" : "=v"(W2) : "v"(st[n2][8*c+4]), "v"(st[n2][8*c+5]));
        asm("v_cvt_pk_bf16_f32 %0, %1, %2" : "=v"(W3) : "v"(st[n2][8*c+6]), "v"(st[n2][8*c+7]));
        int X0 = __shfl_xor(W0, 32), X1 = __shfl_xor(W1, 32);
        int X2 = __shfl_xor(W2, 32), X3 = __shfl_xor(W3, 32);
        union { int u[4]; bf16x8 v; } fr;
        fr.u[0] = hi ? X2 : W0;
        fr.u[1] = hi ? X3 : W1;
        fr.u[2] = hi ? W2 : X0;
        fr.u[3] = hi ? W3 : X1;
#pragma unroll
        for (int dt = 0; dt < 2; ++dt) {
          int rv = dt * 32 + lq;
          bf16x8 vf = *(const bf16x8*)((const char*)Vt +
                         ((rv * 128 + cg * 32 + hi * 16) ^ ((rv & 7) << 4)));
          ot[dt] = __builtin_amdgcn_mfma_f32_32x32x16_bf16(vf, fr.v, ot[dt], 0, 0, 0);
        }
      }
    }
  }
  // epilogue: transpose O^T -> row-major via per-wave LDS slice, store bf16
  __syncthreads();
  u16* wbuf = smem + wave * 2048;   // [32 q][64 d] u16, 8B-chunk XOR swizzled
  float inv = 1.f / li;
#pragma unroll
  for (int dt = 0; dt < 2; ++dt)
#pragma unroll
    for (int g = 0; g < 4; ++g) {
      int p0, p1;
      asm("v_cvt_pk_bf16_f32 %0, %1, %2" : "=v"(p0) : "v"(ot[dt][4*g+0]*inv), "v"(ot[dt][4*g+1]*inv));
      asm("v_cvt_pk_bf16_f32 %0, %1, %2" : "=v"(p1) : "v"(ot[dt][4*g+2]*inv), "v"(ot[dt][4*g+3]*inv));
      int ch = dt * 8 + 2 * g + hi;          // d/4
      int pos = ch ^ ((lq & 7) << 1);
      uint2 wv; wv.x = (unsigned)p0; wv.y = (unsigned)p1;
      *(uint2*)((char*)wbuf + lq * 128 + pos * 8) = wv;
    }
  int q2 = lane >> 1, j0 = lane & 1;
#pragma unroll
  for (int jj = 0; jj < 4; ++jj) {
    int j = j0 + jj * 2;
    uint4 val = *(const uint4*)((const char*)wbuf + q2 * 128 + ((j ^ (q2 & 7)) << 4));
    *(uint4*)(o + (size_t)(b * 1024 + qrow0 + q2) * 512 + h * 64 + j * 8) = val;
  }
}

extern "C" void kernel_launch(void* const* d_in, const int* in_sizes, int n_in,
                              void* d_out, int out_size, void* d_ws, size_t ws_size,
                              hipStream_t stream) {
  const float* x    = (const float*)d_in[0];
  const float* gn_w = (const float*)d_in[1];
  const float* gn_b = (const float*)d_in[2];
  const float* wq   = (const float*)d_in[3];
  const float* bq   = (const float*)d_in[4];
  const float* wk   = (const float*)d_in[5];
  const float* bk   = (const float*)d_in[6];
  const float* wv   = (const float*)d_in[7];
  const float* bv   = (const float*)d_in[8];
  const float* wp   = (const float*)d_in[9];
  const float* bp   = (const float*)d_in[10];

  char* ws = (char*)d_ws;
  float* stats = (float*)ws;                         // 512 B
  float* part  = (float*)(ws + 512);                 // 4 KB
  float* bqk   = (float*)(ws + 4608);                // 4 KB
  u16* wqkb = (u16*)(ws + 8704);                     // 1 MB  [1024][512]
  u16* wvb  = (u16*)(ws + 1057280);                  // 512 KB
  u16* wpb  = (u16*)(ws + 1581568);                  // 512 KB
  u16* xn   = (u16*)(ws + 2105856);                  // 8 MB  [8192][512]
  u16* qkb  = (u16*)(ws + 10494464);                 // 16 MB [8192][1024]
  u16* vTb  = (u16*)(ws + 27271680);                 // 8 MB  [512][8192]
  u16* attno = xn;                                   // alias: xn dead after V GEMM

  gn_partial<<<512, 256, 0, stream>>>(x, part);
  gn_finish<<<1, 64, 0, stream>>>(part, stats);
  gn_apply<<<dim3(32, 16, 8), dim3(32, 8), 0, stream>>>(x, stats, gn_w, gn_b, xn);
  cvt_w<<<1024, 256, 0, stream>>>((const float4*)wq, (const float4*)wk,
                                  (const float4*)wv, (const float4*)wp,
                                  bq, bk, wqkb, wvb, wpb, bqk);
  gemm_nt<<<dim3(64, 8), 256, 0, stream>>>(xn, wqkb, bqk, qkb, 8192, 1024, 512);
  gemm_tn2<<<dim3(128, 4), 256, 0, stream>>>(wvb, xn, bv, nullptr, vTb, 8192, 512, 0);
  attn_fwd<<<dim3(8, 64), 256, 0, stream>>>(qkb, vTb, attno);
  gemm_tn2<<<dim3(128, 4), 256, 0, stream>>>(wpb, attno, bp, x, d_out, 8192, 512, 1);
}

// Round 3
// 109.496 us; speedup vs baseline: 1.3916x; 1.0533x over previous
//
#include <hip/hip_runtime.h>
#include <stdint.h>

typedef unsigned short u16;
using bf16x8 = __attribute__((ext_vector_type(8))) short;
using f32x4  = __attribute__((ext_vector_type(4))) float;
using f32x16 = __attribute__((ext_vector_type(16))) float;
typedef unsigned int uv2 __attribute__((ext_vector_type(2)));

#define EPS_GN 1e-5f
#define SCL 0.18033688011112042f   // 0.125 * log2(e)

__device__ __forceinline__ u16 f2bf(float f) {
  union { float f; uint32_t u; } x; x.f = f;
  uint32_t r = x.u + 0x7FFFu + ((x.u >> 16) & 1u);
  return (u16)(r >> 16);
}

__device__ __forceinline__ void gload_lds16(const void* g, void* l) {
  __builtin_amdgcn_global_load_lds(
      (const __attribute__((address_space(1))) unsigned int*)g,
      (__attribute__((address_space(3))) unsigned int*)l, 16, 0, 0);
}

__device__ __forceinline__ void fence_tile() {
  asm volatile("s_waitcnt vmcnt(0)" ::: "memory");
  __builtin_amdgcn_s_barrier();
  __builtin_amdgcn_sched_barrier(0);
}

// ---------------- GroupNorm ----------------
__global__ __launch_bounds__(256) void gn_partial(const float* __restrict__ x,
                                                  float* __restrict__ part) {
  int bg = blockIdx.x >> 3, seg = blockIdx.x & 7;
  const float4* base = (const float4*)(x + (size_t)bg * 65536 + (size_t)seg * 8192);
  float s = 0.f, s2 = 0.f;
  for (int i = threadIdx.x; i < 2048; i += 256) {
    float4 v = base[i];
    s  += v.x + v.y + v.z + v.w;
    s2 += v.x*v.x + v.y*v.y + v.z*v.z + v.w*v.w;
  }
  for (int m = 1; m < 64; m <<= 1) { s += __shfl_xor(s, m); s2 += __shfl_xor(s2, m); }
  __shared__ float red[4][2];
  int wave = threadIdx.x >> 6;
  if ((threadIdx.x & 63) == 0) { red[wave][0] = s; red[wave][1] = s2; }
  __syncthreads();
  if (threadIdx.x == 0) {
    float a = 0.f, b = 0.f;
    for (int w = 0; w < 4; ++w) { a += red[w][0]; b += red[w][1]; }
    part[blockIdx.x * 2] = a; part[blockIdx.x * 2 + 1] = b;
  }
}

__global__ void gn_finish(const float* __restrict__ part, float* __restrict__ stats) {
  int bg = threadIdx.x;  // 64 threads
  float s = 0.f, s2 = 0.f;
  for (int i = 0; i < 8; ++i) { s += part[(bg*8+i)*2]; s2 += part[(bg*8+i)*2 + 1]; }
  float mean = s * (1.f/65536.f);
  float var  = s2 * (1.f/65536.f) - mean*mean;
  stats[bg*2]   = mean;
  stats[bg*2+1] = rsqrtf(var + EPS_GN);
}

// normalize + transpose [B,C,S] -> xn bf16 [B,S,C]
__global__ __launch_bounds__(256) void gn_apply(const float* __restrict__ x,
    const float* __restrict__ stats, const float* __restrict__ w,
    const float* __restrict__ bb, u16* __restrict__ xn) {
  __shared__ float t[32][33];
  int s0 = blockIdx.x * 32, c0 = blockIdx.y * 32, b = blockIdx.z;
  for (int i = 0; i < 4; ++i) {
    int c = c0 + threadIdx.y + i * 8;
    int g = c >> 6;
    float mean = stats[(b*8+g)*2], rstd = stats[(b*8+g)*2+1];
    float v = x[((size_t)b*512 + c)*1024 + s0 + threadIdx.x];
    t[threadIdx.y + i*8][threadIdx.x] = (v - mean) * rstd * w[c] + bb[c];
  }
  __syncthreads();
  for (int i = 0; i < 4; ++i) {
    int s = s0 + threadIdx.y + i * 8;
    xn[((size_t)b*1024 + s)*512 + c0 + threadIdx.x] = f2bf(t[threadIdx.x][threadIdx.y + i*8]);
  }
}

// ---------------- weights fp32->bf16 (+ scale fold on wq, bias concat) ----------------
__global__ __launch_bounds__(256) void cvt_w(const float4* __restrict__ wq,
    const float4* __restrict__ wk, const float4* __restrict__ wv,
    const float4* __restrict__ wp, const float* __restrict__ bq,
    const float* __restrict__ bk, u16* __restrict__ wqkb, u16* __restrict__ wvb,
    u16* __restrict__ wpb, float* __restrict__ bqk) {
  int i = blockIdx.x * 256 + threadIdx.x;      // 262144 threads
  int seg = i >> 16, j = i & 65535;
  const float4* w = (seg == 0) ? wq : (seg == 1) ? wk : (seg == 2) ? wv : wp;
  u16* o = (seg == 0) ? wqkb : (seg == 1) ? (wqkb + 262144) : (seg == 2) ? wvb : wpb;
  float sc = (seg == 0) ? SCL : 1.f;
  float4 v = w[j];
  o[j*4+0] = f2bf(v.x*sc); o[j*4+1] = f2bf(v.y*sc);
  o[j*4+2] = f2bf(v.z*sc); o[j*4+3] = f2bf(v.w*sc);
  if (i < 1024) bqk[i] = (i < 512) ? bq[i]*SCL : bk[i-512];
}

// ---------------- GEMM (normal): Out[m][n] = X[m][:]·W[n][:] + bias[n], bf16 out ----------------
// 128x128 tile, BK=64, double-buffered LDS, both-sides XOR swizzle.
__global__ __launch_bounds__(256) void gemm_nt(const u16* __restrict__ X,
    const u16* __restrict__ W, const float* __restrict__ bias,
    u16* __restrict__ Out, int M, int N, int K) {
  __shared__ __align__(16) u16 As[2*128*64];
  __shared__ __align__(16) u16 Bs[2*128*64];
  int m0 = blockIdx.x * 128, n0 = blockIdx.y * 128;
  int t = threadIdx.x, lane = t & 63, wave = t >> 6;
  int wm = wave >> 1, wn = wave & 1;
  int lr = lane & 15, lg = lane >> 4;
  f32x4 acc[4][4] = {};

  auto stage = [&](int k0, int bufi) {
    u16* Ab = As + bufi * 8192;
    u16* Bb = Bs + bufi * 8192;
#pragma unroll
    for (int c = 0; c < 4; ++c) {
      int chunk = wave * 4 + c;
      int e = chunk * 512 + lane * 8;
      int r = e >> 6, col = e & 63;
      int scol = col ^ ((r & 7) << 3);
      gload_lds16(X + (size_t)(m0 + r) * K + k0 + scol, (char*)Ab + chunk * 1024);
      gload_lds16(W + (size_t)(n0 + r) * K + k0 + scol, (char*)Bb + chunk * 1024);
    }
  };

  stage(0, 0);
  fence_tile();
  int buf = 0;
  for (int k0 = 0; k0 < K; k0 += 64) {
    if (k0 + 64 < K) stage(k0 + 64, buf ^ 1);
    const char* Ab = (const char*)(As + buf * 8192);
    const char* Bb = (const char*)(Bs + buf * 8192);
    bf16x8 af[4][2], bfr[4][2];
#pragma unroll
    for (int i = 0; i < 4; ++i)
#pragma unroll
      for (int kk = 0; kk < 2; ++kk) {
        int ra = wm * 64 + i * 16 + lr;
        int ca = kk * 64 + lg * 16;
        af[i][kk]  = *(const bf16x8*)(Ab + ((ra * 128 + ca) ^ ((ra & 7) << 4)));
        int rb = wn * 64 + i * 16 + lr;
        bfr[i][kk] = *(const bf16x8*)(Bb + ((rb * 128 + ca) ^ ((rb & 7) << 4)));
      }
    __builtin_amdgcn_s_setprio(1);
#pragma unroll
    for (int kk = 0; kk < 2; ++kk)
#pragma unroll
      for (int i = 0; i < 4; ++i)
#pragma unroll
        for (int j = 0; j < 4; ++j)
          acc[i][j] = __builtin_amdgcn_mfma_f32_16x16x32_bf16(af[i][kk], bfr[j][kk], acc[i][j], 0, 0, 0);
    __builtin_amdgcn_s_setprio(0);
    fence_tile();
    buf ^= 1;
  }
  for (int i = 0; i < 4; ++i)
    for (int j = 0; j < 4; ++j) {
      int col = n0 + wn * 64 + j * 16 + lr;
      float bv = bias[col];
      int rowb = m0 + wm * 64 + i * 16 + lg * 4;
      for (int r = 0; r < 4; ++r)
        Out[(size_t)(rowb + r) * N + col] = f2bf(acc[i][j][r] + bv);
    }
}

// ---------------- GEMM (swapped): C^T[n][m] = W[n][:]·X[m][:] + bias[n] ----------------
// 128(n) x 64(m) tiles -> grid (M/64, N/128). mode 0: bf16 [N][M]; mode 1: fp32 [B][C][S] + resid.
__global__ __launch_bounds__(256) void gemm_tn2(const u16* __restrict__ Wt,
    const u16* __restrict__ X, const float* __restrict__ bias,
    const float* __restrict__ resid, void* __restrict__ Out,
    int M, int K, int mode) {
  __shared__ __align__(16) u16 As[2*128*64];
  __shared__ __align__(16) u16 Bs[2*64*64];
  int m0 = blockIdx.x * 64, n0 = blockIdx.y * 128;
  int t = threadIdx.x, lane = t & 63, wave = t >> 6;
  int wm = wave >> 1, wn = wave & 1;
  int lr = lane & 15, lg = lane >> 4;
  f32x4 acc[4][2] = {};

  auto stage = [&](int k0, int bufi) {
    u16* Ab = As + bufi * 8192;
    u16* Bb = Bs + bufi * 4096;
#pragma unroll
    for (int c = 0; c < 4; ++c) {
      int chunk = wave * 4 + c;
      int e = chunk * 512 + lane * 8;
      int r = e >> 6, col = e & 63;
      int scol = col ^ ((r & 7) << 3);
      gload_lds16(Wt + (size_t)(n0 + r) * K + k0 + scol, (char*)Ab + chunk * 1024);
    }
#pragma unroll
    for (int c = 0; c < 2; ++c) {
      int chunk = wave * 2 + c;
      int e = chunk * 512 + lane * 8;
      int r = e >> 6, col = e & 63;
      int scol = col ^ ((r & 7) << 3);
      gload_lds16(X + (size_t)(m0 + r) * K + k0 + scol, (char*)Bb + chunk * 1024);
    }
  };

  stage(0, 0);
  fence_tile();
  int buf = 0;
  for (int k0 = 0; k0 < K; k0 += 64) {
    if (k0 + 64 < K) stage(k0 + 64, buf ^ 1);
    const char* Ab = (const char*)(As + buf * 8192);
    const char* Bb = (const char*)(Bs + buf * 4096);
    bf16x8 af[4][2], bfr[2][2];
#pragma unroll
    for (int kk = 0; kk < 2; ++kk) {
      int ca = kk * 64 + lg * 16;
#pragma unroll
      for (int i = 0; i < 4; ++i) {
        int ra = wm * 64 + i * 16 + lr;
        af[i][kk] = *(const bf16x8*)(Ab + ((ra * 128 + ca) ^ ((ra & 7) << 4)));
      }
#pragma unroll
      for (int j = 0; j < 2; ++j) {
        int rb = wn * 32 + j * 16 + lr;
        bfr[j][kk] = *(const bf16x8*)(Bb + ((rb * 128 + ca) ^ ((rb & 7) << 4)));
      }
    }
    __builtin_amdgcn_s_setprio(1);
#pragma unroll
    for (int kk = 0; kk < 2; ++kk)
#pragma unroll
      for (int i = 0; i < 4; ++i)
#pragma unroll
        for (int j = 0; j < 2; ++j)
          acc[i][j] = __builtin_amdgcn_mfma_f32_16x16x32_bf16(af[i][kk], bfr[j][kk], acc[i][j], 0, 0, 0);
    __builtin_amdgcn_s_setprio(0);
    fence_tile();
    buf ^= 1;
  }
  for (int i = 0; i < 4; ++i)
    for (int j = 0; j < 2; ++j) {
      int mcol = m0 + wn * 32 + j * 16 + lr;
      for (int r = 0; r < 4; ++r) {
        int nrow = n0 + wm * 64 + i * 16 + lg * 4 + r;
        float v = acc[i][j][r] + bias[nrow];
        if (mode == 0) {
          ((u16*)Out)[(size_t)nrow * M + mcol] = f2bf(v);
        } else {
          size_t b = (size_t)(mcol >> 10); int s = mcol & 1023;
          size_t addr = (b * 512 + nrow) * 1024 + s;
          ((float*)Out)[addr] = v + resid[addr];
        }
      }
    }
}

// ---------------- flash attention, swapped 32x32, double-buffered ----------------
// grid (8 q-blocks of 128, 64 b*h); 4 waves x 32 q-rows; KV tiles of 64.
__global__ __launch_bounds__(256) void attn_fwd(const u16* __restrict__ qk,
    const u16* __restrict__ vT, u16* __restrict__ o) {
  __shared__ __align__(16) u16 smem[16384];      // 2 x (Ks 8KB | Vt 8KB)
  int qb = blockIdx.x, bh = blockIdx.y;
  int b = bh >> 3, h = bh & 7;
  int t = threadIdx.x, lane = t & 63, wave = t >> 6;
  int lq = lane & 31, hi = lane >> 5;
  int qrow0 = qb * 128 + wave * 32;
  const u16* qp = qk + (size_t)(b * 1024 + qrow0 + lq) * 1024 + h * 64 + hi * 8;
  bf16x8 qf[4];
#pragma unroll
  for (int s = 0; s < 4; ++s) qf[s] = *(const bf16x8*)(qp + s * 16);
  float mi = -1e30f, li = 0.f;
  f32x16 ot[2] = {};

  auto stage = [&](int ti, int bufi) {
    u16* Kb = smem + bufi * 8192;
    u16* Vb = Kb + 4096;
    int kv = ti * 64;
#pragma unroll
    for (int c = 0; c < 2; ++c) {
      int chunk = wave * 2 + c;
      int e = chunk * 512 + lane * 8;
      int r = e >> 6, col = e & 63;
      int scol = col ^ ((r & 7) << 3);
      gload_lds16(qk + (size_t)(b * 1024 + kv + r) * 1024 + 512 + h * 64 + scol,
                  (char*)Kb + chunk * 1024);
      gload_lds16(vT + (size_t)(h * 64 + r) * 8192 + b * 1024 + kv + scol,
                  (char*)Vb + chunk * 1024);
    }
  };

  stage(0, 0);
  fence_tile();
  int buf = 0;
  for (int ti = 0; ti < 16; ++ti) {
    if (ti < 15) stage(ti + 1, buf ^ 1);
    const char* Kb = (const char*)(smem + buf * 8192);
    const char* Vb = Kb + 8192;
    // S^T tiles: st[n2] = K[n2*32..+31][:] · Q^T
    f32x16 st[2];
#pragma unroll
    for (int n2 = 0; n2 < 2; ++n2) {
      int rk = n2 * 32 + lq;
      f32x16 z = {};
      __builtin_amdgcn_s_setprio(1);
#pragma unroll
      for (int s = 0; s < 4; ++s) {
        bf16x8 kf = *(const bf16x8*)(Kb + ((rk * 128 + s * 32 + hi * 16) ^ ((rk & 7) << 4)));
        z = __builtin_amdgcn_mfma_f32_32x32x16_bf16(kf, qf[s], z, 0, 0, 0);
      }
      __builtin_amdgcn_s_setprio(0);
      st[n2] = z;
    }
    // online softmax (log2 units)
    float a[16];
#pragma unroll
    for (int r = 0; r < 16; ++r) a[r] = fmaxf(st[0][r], st[1][r]);
#pragma unroll
    for (int s = 8; s > 0; s >>= 1)
#pragma unroll
      for (int r = 0; r < s; ++r) a[r] = fmaxf(a[r], a[r + s]);
    float mx = fmaxf(a[0], __shfl_xor(a[0], 32));
    if (!__all(mx <= mi + 10.f)) {     // defer-max (T13)
      float nm = fmaxf(mi, mx);
      float al = exp2f(mi - nm);
      li *= al;
#pragma unroll
      for (int r = 0; r < 16; ++r) { ot[0][r] *= al; ot[1][r] *= al; }
      mi = nm;
    }
    float sm[16];
#pragma unroll
    for (int r = 0; r < 16; ++r) {
      float e0 = exp2f(st[0][r] - mi);
      float e1 = exp2f(st[1][r] - mi);
      st[0][r] = e0; st[1][r] = e1;
      sm[r] = e0 + e1;
    }
#pragma unroll
    for (int s = 8; s > 0; s >>= 1)
#pragma unroll
      for (int r = 0; r < s; ++r) sm[r] += sm[r + s];
    li += sm[0] + __shfl_xor(sm[0], 32);
    // PV: ot[dt] += V^T · P  (P fragments via cvt_pk + permlane32_swap)
#pragma unroll
    for (int n2 = 0; n2 < 2; ++n2) {
#pragma unroll
      for (int c = 0; c < 2; ++c) {
        int cg = n2 * 2 + c;
        unsigned W0, W1, W2, W3;
        asm("v_cvt_pk_bf16_f32 %0, %1, %2" : "=v"(W0) : "v"(st[n2][8*c+0]), "v"(st[n2][8*c+1]));
        asm("v_cvt_pk_bf16_f32 %0, %1, %2" : "=v"(W1) : "v"(st[n2][8*c+2]), "v"(st[n2][8*c+3]));
        asm("v_cvt_pk_bf16_f32 %0, %1, %2" : "=v"(W2) : "v"(st[n2][8*c+4]), "v"(st[n2][8*c+5]));
        asm("v_cvt_pk_bf16_f32 %0, %1, %2" : "=v"(W3) : "v"(st[n2][8*c+6]), "v"(st[n2][8*c+7]));
        uv2 r02 = __builtin_amdgcn_permlane32_swap(W0, W2, false, false);
        uv2 r13 = __builtin_amdgcn_permlane32_swap(W1, W3, false, false);
        union { unsigned u[4]; bf16x8 v; } fr;
        fr.u[0] = r02[0]; fr.u[1] = r13[0]; fr.u[2] = r02[1]; fr.u[3] = r13[1];
        __builtin_amdgcn_s_setprio(1);
#pragma unroll
        for (int dt = 0; dt < 2; ++dt) {
          int rv = dt * 32 + lq;
          bf16x8 vf = *(const bf16x8*)(Vb + ((rv * 128 + cg * 32 + hi * 16) ^ ((rv & 7) << 4)));
          ot[dt] = __builtin_amdgcn_mfma_f32_32x32x16_bf16(vf, fr.v, ot[dt], 0, 0, 0);
        }
        __builtin_amdgcn_s_setprio(0);
      }
    }
    fence_tile();
    buf ^= 1;
  }
  // epilogue: transpose O^T -> row-major via per-wave LDS slice, store bf16
  __syncthreads();
  u16* wbuf = smem + wave * 2048;   // [32 q][64 d] u16, 8B-chunk XOR swizzled
  float inv = 1.f / li;
#pragma unroll
  for (int dt = 0; dt < 2; ++dt)
#pragma unroll
    for (int g = 0; g < 4; ++g) {
      unsigned p0, p1;
      asm("v_cvt_pk_bf16_f32 %0, %1, %2" : "=v"(p0) : "v"(ot[dt][4*g+0]*inv), "v"(ot[dt][4*g+1]*inv));
      asm("v_cvt_pk_bf16_f32 %0, %1, %2" : "=v"(p1) : "v"(ot[dt][4*g+2]*inv), "v"(ot[dt][4*g+3]*inv));
      int ch = dt * 8 + 2 * g + hi;          // d/4
      int pos = ch ^ ((lq & 7) << 1);
      uint2 wv; wv.x = p0; wv.y = p1;
      *(uint2*)((char*)wbuf + lq * 128 + pos * 8) = wv;
    }
  int q2 = lane >> 1, j0 = lane & 1;
#pragma unroll
  for (int jj = 0; jj < 4; ++jj) {
    int j = j0 + jj * 2;
    uint4 val = *(const uint4*)((const char*)wbuf + q2 * 128 + ((j ^ (q2 & 7)) << 4));
    *(uint4*)(o + (size_t)(b * 1024 + qrow0 + q2) * 512 + h * 64 + j * 8) = val;
  }
}

extern "C" void kernel_launch(void* const* d_in, const int* in_sizes, int n_in,
                              void* d_out, int out_size, void* d_ws, size_t ws_size,
                              hipStream_t stream) {
  const float* x    = (const float*)d_in[0];
  const float* gn_w = (const float*)d_in[1];
  const float* gn_b = (const float*)d_in[2];
  const float* wq   = (const float*)d_in[3];
  const float* bq   = (const float*)d_in[4];
  const float* wk   = (const float*)d_in[5];
  const float* bk   = (const float*)d_in[6];
  const float* wv   = (const float*)d_in[7];
  const float* bv   = (const float*)d_in[8];
  const float* wp   = (const float*)d_in[9];
  const float* bp   = (const float*)d_in[10];

  char* ws = (char*)d_ws;
  float* stats = (float*)ws;                         // 512 B
  float* part  = (float*)(ws + 512);                 // 4 KB
  float* bqk   = (float*)(ws + 4608);                // 4 KB
  u16* wqkb = (u16*)(ws + 8704);                     // 1 MB  [1024][512]
  u16* wvb  = (u16*)(ws + 1057280);                  // 512 KB
  u16* wpb  = (u16*)(ws + 1581568);                  // 512 KB
  u16* xn   = (u16*)(ws + 2105856);                  // 8 MB  [8192][512]
  u16* qkb  = (u16*)(ws + 10494464);                 // 16 MB [8192][1024]
  u16* vTb  = (u16*)(ws + 27271680);                 // 8 MB  [512][8192]
  u16* attno = xn;                                   // alias: xn dead after V GEMM

  gn_partial<<<512, 256, 0, stream>>>(x, part);
  gn_finish<<<1, 64, 0, stream>>>(part, stats);
  gn_apply<<<dim3(32, 16, 8), dim3(32, 8), 0, stream>>>(x, stats, gn_w, gn_b, xn);
  cvt_w<<<1024, 256, 0, stream>>>((const float4*)wq, (const float4*)wk,
                                  (const float4*)wv, (const float4*)wp,
                                  bq, bk, wqkb, wvb, wpb, bqk);
  gemm_nt<<<dim3(64, 8), 256, 0, stream>>>(xn, wqkb, bqk, qkb, 8192, 1024, 512);
  gemm_tn2<<<dim3(128, 4), 256, 0, stream>>>(wvb, xn, bv, nullptr, vTb, 8192, 512, 0);
  attn_fwd<<<dim3(8, 64), 256, 0, stream>>>(qkb, vTb, attno);
  gemm_tn2<<<dim3(128, 4), 256, 0, stream>>>(wpb, attno, bp, x, d_out, 8192, 512, 1);
}

// Round 4
// 101.243 us; speedup vs baseline: 1.5051x; 1.0815x over previous
//
#include <hip/hip_runtime.h>
#include <stdint.h>

typedef unsigned short u16;
using bf16x8 = __attribute__((ext_vector_type(8))) short;
using f32x4  = __attribute__((ext_vector_type(4))) float;
using f32x16 = __attribute__((ext_vector_type(16))) float;
typedef unsigned int uv2 __attribute__((ext_vector_type(2)));

#define EPS_GN 1e-5f
#define SCL 0.18033688011112042f   // 0.125 * log2(e)

__device__ __forceinline__ u16 f2bf(float f) {
  union { float f; uint32_t u; } x; x.f = f;
  uint32_t r = x.u + 0x7FFFu + ((x.u >> 16) & 1u);
  return (u16)(r >> 16);
}

__device__ __forceinline__ void gload_lds16(const void* g, void* l) {
  __builtin_amdgcn_global_load_lds(
      (const __attribute__((address_space(1))) unsigned int*)g,
      (__attribute__((address_space(3))) unsigned int*)l, 16, 0, 0);
}

__device__ __forceinline__ void fence_tile() {
  asm volatile("s_waitcnt vmcnt(0)" ::: "memory");
  __builtin_amdgcn_s_barrier();
  __builtin_amdgcn_sched_barrier(0);
}

// ---------------- GroupNorm ----------------
__global__ __launch_bounds__(256) void gn_partial(const float* __restrict__ x,
                                                  float* __restrict__ part) {
  int bg = blockIdx.x >> 3, seg = blockIdx.x & 7;
  const float4* base = (const float4*)(x + (size_t)bg * 65536 + (size_t)seg * 8192);
  float s = 0.f, s2 = 0.f;
  for (int i = threadIdx.x; i < 2048; i += 256) {
    float4 v = base[i];
    s  += v.x + v.y + v.z + v.w;
    s2 += v.x*v.x + v.y*v.y + v.z*v.z + v.w*v.w;
  }
  for (int m = 1; m < 64; m <<= 1) { s += __shfl_xor(s, m); s2 += __shfl_xor(s2, m); }
  __shared__ float red[4][2];
  int wave = threadIdx.x >> 6;
  if ((threadIdx.x & 63) == 0) { red[wave][0] = s; red[wave][1] = s2; }
  __syncthreads();
  if (threadIdx.x == 0) {
    float a = 0.f, b = 0.f;
    for (int w = 0; w < 4; ++w) { a += red[w][0]; b += red[w][1]; }
    part[blockIdx.x * 2] = a; part[blockIdx.x * 2 + 1] = b;
  }
}

__global__ void gn_finish(const float* __restrict__ part, float* __restrict__ stats) {
  int bg = threadIdx.x;  // 64 threads
  float s = 0.f, s2 = 0.f;
  for (int i = 0; i < 8; ++i) { s += part[(bg*8+i)*2]; s2 += part[(bg*8+i)*2 + 1]; }
  float mean = s * (1.f/65536.f);
  float var  = s2 * (1.f/65536.f) - mean*mean;
  stats[bg*2]   = mean;
  stats[bg*2+1] = rsqrtf(var + EPS_GN);
}

// normalize + transpose [B,C,S] -> xn bf16 [B,S,C]
__global__ __launch_bounds__(256) void gn_apply(const float* __restrict__ x,
    const float* __restrict__ stats, const float* __restrict__ w,
    const float* __restrict__ bb, u16* __restrict__ xn) {
  __shared__ float t[32][33];
  int s0 = blockIdx.x * 32, c0 = blockIdx.y * 32, b = blockIdx.z;
  for (int i = 0; i < 4; ++i) {
    int c = c0 + threadIdx.y + i * 8;
    int g = c >> 6;
    float mean = stats[(b*8+g)*2], rstd = stats[(b*8+g)*2+1];
    float v = x[((size_t)b*512 + c)*1024 + s0 + threadIdx.x];
    t[threadIdx.y + i*8][threadIdx.x] = (v - mean) * rstd * w[c] + bb[c];
  }
  __syncthreads();
  for (int i = 0; i < 4; ++i) {
    int s = s0 + threadIdx.y + i * 8;
    xn[((size_t)b*1024 + s)*512 + c0 + threadIdx.x] = f2bf(t[threadIdx.x][threadIdx.y + i*8]);
  }
}

// ---------------- weights fp32->bf16 (+ scale fold on wq, bias concat) ----------------
__global__ __launch_bounds__(256) void cvt_w(const float4* __restrict__ wq,
    const float4* __restrict__ wk, const float4* __restrict__ wv,
    const float4* __restrict__ wp, const float* __restrict__ bq,
    const float* __restrict__ bk, u16* __restrict__ wqkb, u16* __restrict__ wvb,
    u16* __restrict__ wpb, float* __restrict__ bqk) {
  int i = blockIdx.x * 256 + threadIdx.x;      // 262144 threads
  int seg = i >> 16, j = i & 65535;
  const float4* w = (seg == 0) ? wq : (seg == 1) ? wk : (seg == 2) ? wv : wp;
  u16* o = (seg == 0) ? wqkb : (seg == 1) ? (wqkb + 262144) : (seg == 2) ? wvb : wpb;
  float sc = (seg == 0) ? SCL : 1.f;
  float4 v = w[j];
  o[j*4+0] = f2bf(v.x*sc); o[j*4+1] = f2bf(v.y*sc);
  o[j*4+2] = f2bf(v.z*sc); o[j*4+3] = f2bf(v.w*sc);
  if (i < 1024) bqk[i] = (i < 512) ? bq[i]*SCL : bk[i-512];
}

// ---------------- GEMM (normal): Out[m][n] = X[m][:]·W[n][:] + bias[n], bf16 out ----------------
__global__ __launch_bounds__(256) void gemm_nt(const u16* __restrict__ X,
    const u16* __restrict__ W, const float* __restrict__ bias,
    u16* __restrict__ Out, int M, int N, int K) {
  __shared__ __align__(16) u16 As[2*128*64];
  __shared__ __align__(16) u16 Bs[2*128*64];
  int m0 = blockIdx.x * 128, n0 = blockIdx.y * 128;
  int t = threadIdx.x, lane = t & 63, wave = t >> 6;
  int wm = wave >> 1, wn = wave & 1;
  int lr = lane & 15, lg = lane >> 4;
  f32x4 acc[4][4] = {};

  auto stage = [&](int k0, int bufi) {
    u16* Ab = As + bufi * 8192;
    u16* Bb = Bs + bufi * 8192;
#pragma unroll
    for (int c = 0; c < 4; ++c) {
      int chunk = wave * 4 + c;
      int e = chunk * 512 + lane * 8;
      int r = e >> 6, col = e & 63;
      int scol = col ^ ((r & 7) << 3);
      gload_lds16(X + (size_t)(m0 + r) * K + k0 + scol, (char*)Ab + chunk * 1024);
      gload_lds16(W + (size_t)(n0 + r) * K + k0 + scol, (char*)Bb + chunk * 1024);
    }
  };

  stage(0, 0);
  fence_tile();
  int buf = 0;
  for (int k0 = 0; k0 < K; k0 += 64) {
    if (k0 + 64 < K) stage(k0 + 64, buf ^ 1);
    const char* Ab = (const char*)(As + buf * 8192);
    const char* Bb = (const char*)(Bs + buf * 8192);
    bf16x8 af[4][2], bfr[4][2];
#pragma unroll
    for (int i = 0; i < 4; ++i)
#pragma unroll
      for (int kk = 0; kk < 2; ++kk) {
        int ra = wm * 64 + i * 16 + lr;
        int ca = kk * 64 + lg * 16;
        af[i][kk]  = *(const bf16x8*)(Ab + ((ra * 128 + ca) ^ ((ra & 7) << 4)));
        int rb = wn * 64 + i * 16 + lr;
        bfr[i][kk] = *(const bf16x8*)(Bb + ((rb * 128 + ca) ^ ((rb & 7) << 4)));
      }
    __builtin_amdgcn_s_setprio(1);
#pragma unroll
    for (int kk = 0; kk < 2; ++kk)
#pragma unroll
      for (int i = 0; i < 4; ++i)
#pragma unroll
        for (int j = 0; j < 4; ++j)
          acc[i][j] = __builtin_amdgcn_mfma_f32_16x16x32_bf16(af[i][kk], bfr[j][kk], acc[i][j], 0, 0, 0);
    __builtin_amdgcn_s_setprio(0);
    fence_tile();
    buf ^= 1;
  }
  for (int i = 0; i < 4; ++i)
    for (int j = 0; j < 4; ++j) {
      int col = n0 + wn * 64 + j * 16 + lr;
      float bv = bias[col];
      int rowb = m0 + wm * 64 + i * 16 + lg * 4;
      for (int r = 0; r < 4; ++r)
        Out[(size_t)(rowb + r) * N + col] = f2bf(acc[i][j][r] + bv);
    }
}

// ---------------- GEMM (swapped): C^T[n][m] = W[n][:]·X[m][:] + bias[n] ----------------
__global__ __launch_bounds__(256) void gemm_tn2(const u16* __restrict__ Wt,
    const u16* __restrict__ X, const float* __restrict__ bias,
    const float* __restrict__ resid, void* __restrict__ Out,
    int M, int K, int mode) {
  __shared__ __align__(16) u16 As[2*128*64];
  __shared__ __align__(16) u16 Bs[2*64*64];
  int m0 = blockIdx.x * 64, n0 = blockIdx.y * 128;
  int t = threadIdx.x, lane = t & 63, wave = t >> 6;
  int wm = wave >> 1, wn = wave & 1;
  int lr = lane & 15, lg = lane >> 4;
  f32x4 acc[4][2] = {};

  auto stage = [&](int k0, int bufi) {
    u16* Ab = As + bufi * 8192;
    u16* Bb = Bs + bufi * 4096;
#pragma unroll
    for (int c = 0; c < 4; ++c) {
      int chunk = wave * 4 + c;
      int e = chunk * 512 + lane * 8;
      int r = e >> 6, col = e & 63;
      int scol = col ^ ((r & 7) << 3);
      gload_lds16(Wt + (size_t)(n0 + r) * K + k0 + scol, (char*)Ab + chunk * 1024);
    }
#pragma unroll
    for (int c = 0; c < 2; ++c) {
      int chunk = wave * 2 + c;
      int e = chunk * 512 + lane * 8;
      int r = e >> 6, col = e & 63;
      int scol = col ^ ((r & 7) << 3);
      gload_lds16(X + (size_t)(m0 + r) * K + k0 + scol, (char*)Bb + chunk * 1024);
    }
  };

  stage(0, 0);
  fence_tile();
  int buf = 0;
  for (int k0 = 0; k0 < K; k0 += 64) {
    if (k0 + 64 < K) stage(k0 + 64, buf ^ 1);
    const char* Ab = (const char*)(As + buf * 8192);
    const char* Bb = (const char*)(Bs + buf * 4096);
    bf16x8 af[4][2], bfr[2][2];
#pragma unroll
    for (int kk = 0; kk < 2; ++kk) {
      int ca = kk * 64 + lg * 16;
#pragma unroll
      for (int i = 0; i < 4; ++i) {
        int ra = wm * 64 + i * 16 + lr;
        af[i][kk] = *(const bf16x8*)(Ab + ((ra * 128 + ca) ^ ((ra & 7) << 4)));
      }
#pragma unroll
      for (int j = 0; j < 2; ++j) {
        int rb = wn * 32 + j * 16 + lr;
        bfr[j][kk] = *(const bf16x8*)(Bb + ((rb * 128 + ca) ^ ((rb & 7) << 4)));
      }
    }
    __builtin_amdgcn_s_setprio(1);
#pragma unroll
    for (int kk = 0; kk < 2; ++kk)
#pragma unroll
      for (int i = 0; i < 4; ++i)
#pragma unroll
        for (int j = 0; j < 2; ++j)
          acc[i][j] = __builtin_amdgcn_mfma_f32_16x16x32_bf16(af[i][kk], bfr[j][kk], acc[i][j], 0, 0, 0);
    __builtin_amdgcn_s_setprio(0);
    fence_tile();
    buf ^= 1;
  }
  for (int i = 0; i < 4; ++i)
    for (int j = 0; j < 2; ++j) {
      int mcol = m0 + wn * 32 + j * 16 + lr;
      for (int r = 0; r < 4; ++r) {
        int nrow = n0 + wm * 64 + i * 16 + lg * 4 + r;
        float v = acc[i][j][r] + bias[nrow];
        if (mode == 0) {
          ((u16*)Out)[(size_t)nrow * M + mcol] = f2bf(v);
        } else {
          size_t b = (size_t)(mcol >> 10); int s = mcol & 1023;
          size_t addr = (b * 512 + nrow) * 1024 + s;
          ((float*)Out)[addr] = v + resid[addr];
        }
      }
    }
}

// ---------------- flash attention, swapped 32x32, in-block KV-split x2 ----------------
// grid (8 q-blocks of 128, 64 b*h); 8 waves: waves 0-3 KV[0,512), waves 4-7 KV[512,1024).
__global__ __launch_bounds__(512, 4) void attn_fwd(const u16* __restrict__ qk,
    const u16* __restrict__ vT, u16* __restrict__ o) {
  __shared__ __align__(16) u16 smem[32768];      // 64KB: [half][buf] x 16KB (K 8KB | V 8KB)
  int qb = blockIdx.x, bh = blockIdx.y;
  int b = bh >> 3, h = bh & 7;
  int t = threadIdx.x, lane = t & 63, wave = t >> 6;
  int half = wave >> 2, wq4 = wave & 3;
  int lq = lane & 31, hi = lane >> 5;
  int qrow0 = qb * 128 + wq4 * 32;
  const u16* qp = qk + (size_t)(b * 1024 + qrow0 + lq) * 1024 + h * 64 + hi * 8;
  bf16x8 qf[4];
#pragma unroll
  for (int s = 0; s < 4; ++s) qf[s] = *(const bf16x8*)(qp + s * 16);
  float mi = -1e30f, li = 0.f;
  f32x16 ot[2] = {};
  int kvbase = half * 512;

  auto stage = [&](int ti, int bufi) {
    u16* Kb = smem + (half * 2 + bufi) * 8192;
    u16* Vb = Kb + 4096;
    int kv = kvbase + ti * 64;
#pragma unroll
    for (int c = 0; c < 2; ++c) {
      int chunk = wq4 * 2 + c;
      int e = chunk * 512 + lane * 8;
      int r = e >> 6, col = e & 63;
      int scol = col ^ ((r & 7) << 3);
      gload_lds16(qk + (size_t)(b * 1024 + kv + r) * 1024 + 512 + h * 64 + scol,
                  (char*)Kb + chunk * 1024);
      gload_lds16(vT + (size_t)(h * 64 + r) * 8192 + b * 1024 + kv + scol,
                  (char*)Vb + chunk * 1024);
    }
  };

  stage(0, 0);
  fence_tile();
  int buf = 0;
  for (int ti = 0; ti < 8; ++ti) {
    if (ti < 7) stage(ti + 1, buf ^ 1);
    const char* Kb = (const char*)(smem + (half * 2 + buf) * 8192);
    const char* Vb = Kb + 8192;
    // S^T tiles: st[n2] = K[n2*32..+31][:] · Q^T
    f32x16 st[2];
#pragma unroll
    for (int n2 = 0; n2 < 2; ++n2) {
      int rk = n2 * 32 + lq;
      f32x16 z = {};
      __builtin_amdgcn_s_setprio(1);
#pragma unroll
      for (int s = 0; s < 4; ++s) {
        bf16x8 kf = *(const bf16x8*)(Kb + ((rk * 128 + s * 32 + hi * 16) ^ ((rk & 7) << 4)));
        z = __builtin_amdgcn_mfma_f32_32x32x16_bf16(kf, qf[s], z, 0, 0, 0);
      }
      __builtin_amdgcn_s_setprio(0);
      st[n2] = z;
    }
    // online softmax (log2 units)
    float a[16];
#pragma unroll
    for (int r = 0; r < 16; ++r) a[r] = fmaxf(st[0][r], st[1][r]);
#pragma unroll
    for (int s = 8; s > 0; s >>= 1)
#pragma unroll
      for (int r = 0; r < s; ++r) a[r] = fmaxf(a[r], a[r + s]);
    float mx = fmaxf(a[0], __shfl_xor(a[0], 32));
    if (!__all(mx <= mi + 10.f)) {     // defer-max (T13)
      float nm = fmaxf(mi, mx);
      float al = __builtin_amdgcn_exp2f(mi - nm);
      li *= al;
#pragma unroll
      for (int r = 0; r < 16; ++r) { ot[0][r] *= al; ot[1][r] *= al; }
      mi = nm;
    }
    float sm[16];
#pragma unroll
    for (int r = 0; r < 16; ++r) {
      float e0 = __builtin_amdgcn_exp2f(st[0][r] - mi);
      float e1 = __builtin_amdgcn_exp2f(st[1][r] - mi);
      st[0][r] = e0; st[1][r] = e1;
      sm[r] = e0 + e1;
    }
#pragma unroll
    for (int s = 8; s > 0; s >>= 1)
#pragma unroll
      for (int r = 0; r < s; ++r) sm[r] += sm[r + s];
    li += sm[0] + __shfl_xor(sm[0], 32);
    // PV: ot[dt] += V^T · P  (P fragments via cvt_pk + permlane32_swap)
#pragma unroll
    for (int n2 = 0; n2 < 2; ++n2) {
#pragma unroll
      for (int c = 0; c < 2; ++c) {
        int cg = n2 * 2 + c;
        unsigned W0, W1, W2, W3;
        asm("v_cvt_pk_bf16_f32 %0, %1, %2" : "=v"(W0) : "v"(st[n2][8*c+0]), "v"(st[n2][8*c+1]));
        asm("v_cvt_pk_bf16_f32 %0, %1, %2" : "=v"(W1) : "v"(st[n2][8*c+2]), "v"(st[n2][8*c+3]));
        asm("v_cvt_pk_bf16_f32 %0, %1, %2" : "=v"(W2) : "v"(st[n2][8*c+4]), "v"(st[n2][8*c+5]));
        asm("v_cvt_pk_bf16_f32 %0, %1, %2" : "=v"(W3) : "v"(st[n2][8*c+6]), "v"(st[n2][8*c+7]));
        uv2 r02 = __builtin_amdgcn_permlane32_swap(W0, W2, false, false);
        uv2 r13 = __builtin_amdgcn_permlane32_swap(W1, W3, false, false);
        union { unsigned u[4]; bf16x8 v; } fr;
        fr.u[0] = r02[0]; fr.u[1] = r13[0]; fr.u[2] = r02[1]; fr.u[3] = r13[1];
        __builtin_amdgcn_s_setprio(1);
#pragma unroll
        for (int dt = 0; dt < 2; ++dt) {
          int rv = dt * 32 + lq;
          bf16x8 vf = *(const bf16x8*)(Vb + ((rv * 128 + cg * 32 + hi * 16) ^ ((rv & 7) << 4)));
          ot[dt] = __builtin_amdgcn_mfma_f32_32x32x16_bf16(vf, fr.v, ot[dt], 0, 0, 0);
        }
        __builtin_amdgcn_s_setprio(0);
      }
    }
    fence_tile();
    buf ^= 1;
  }
  // ---- combine the two KV halves (element-wise: partner lanes hold same (q,d)) ----
  float* cbuf = (float*)smem;
  float* wreg = cbuf + wq4 * 2176;
  if (half == 0) {
#pragma unroll
    for (int dt = 0; dt < 2; ++dt)
#pragma unroll
      for (int r = 0; r < 16; ++r)
        wreg[(dt * 16 + r) * 64 + lane] = ot[dt][r];
    wreg[2048 + lane] = mi;
    wreg[2112 + lane] = li;
  }
  __syncthreads();
  if (half == 1) {
    float m0 = wreg[2048 + lane], l0 = wreg[2112 + lane];
    float m = fmaxf(m0, mi);
    float a0 = __builtin_amdgcn_exp2f(m0 - m);
    float a1 = __builtin_amdgcn_exp2f(mi - m);
    float inv = 1.f / (l0 * a0 + li * a1);
    // epilogue: transpose O^T -> row-major via per-wave LDS slice, store bf16
    u16* wbuf = smem + 18432 + wq4 * 2048;   // [32 q][64 d] u16, 8B-chunk XOR swizzled
#pragma unroll
    for (int dt = 0; dt < 2; ++dt)
#pragma unroll
      for (int g = 0; g < 4; ++g) {
        float v0 = (wreg[(dt*16 + 4*g+0)*64 + lane] * a0 + ot[dt][4*g+0] * a1) * inv;
        float v1 = (wreg[(dt*16 + 4*g+1)*64 + lane] * a0 + ot[dt][4*g+1] * a1) * inv;
        float v2 = (wreg[(dt*16 + 4*g+2)*64 + lane] * a0 + ot[dt][4*g+2] * a1) * inv;
        float v3 = (wreg[(dt*16 + 4*g+3)*64 + lane] * a0 + ot[dt][4*g+3] * a1) * inv;
        unsigned p0, p1;
        asm("v_cvt_pk_bf16_f32 %0, %1, %2" : "=v"(p0) : "v"(v0), "v"(v1));
        asm("v_cvt_pk_bf16_f32 %0, %1, %2" : "=v"(p1) : "v"(v2), "v"(v3));
        int ch = dt * 8 + 2 * g + hi;          // d/4
        int pos = ch ^ ((lq & 7) << 1);
        uint2 wv; wv.x = p0; wv.y = p1;
        *(uint2*)((char*)wbuf + lq * 128 + pos * 8) = wv;
      }
    int q2 = lane >> 1, j0 = lane & 1;
#pragma unroll
    for (int jj = 0; jj < 4; ++jj) {
      int j = j0 + jj * 2;
      uint4 val = *(const uint4*)((const char*)wbuf + q2 * 128 + ((j ^ (q2 & 7)) << 4));
      *(uint4*)(o + (size_t)(b * 1024 + qrow0 + q2) * 512 + h * 64 + j * 8) = val;
    }
  }
}

extern "C" void kernel_launch(void* const* d_in, const int* in_sizes, int n_in,
                              void* d_out, int out_size, void* d_ws, size_t ws_size,
                              hipStream_t stream) {
  const float* x    = (const float*)d_in[0];
  const float* gn_w = (const float*)d_in[1];
  const float* gn_b = (const float*)d_in[2];
  const float* wq   = (const float*)d_in[3];
  const float* bq   = (const float*)d_in[4];
  const float* wk   = (const float*)d_in[5];
  const float* bk   = (const float*)d_in[6];
  const float* wv   = (const float*)d_in[7];
  const float* bv   = (const float*)d_in[8];
  const float* wp   = (const float*)d_in[9];
  const float* bp   = (const float*)d_in[10];

  char* ws = (char*)d_ws;
  float* stats = (float*)ws;                         // 512 B
  float* part  = (float*)(ws + 512);                 // 4 KB
  float* bqk   = (float*)(ws + 4608);                // 4 KB
  u16* wqkb = (u16*)(ws + 8704);                     // 1 MB  [1024][512]
  u16* wvb  = (u16*)(ws + 1057280);                  // 512 KB
  u16* wpb  = (u16*)(ws + 1581568);                  // 512 KB
  u16* xn   = (u16*)(ws + 2105856);                  // 8 MB  [8192][512]
  u16* qkb  = (u16*)(ws + 10494464);                 // 16 MB [8192][1024]
  u16* vTb  = (u16*)(ws + 27271680);                 // 8 MB  [512][8192]
  u16* attno = xn;                                   // alias: xn dead after V GEMM

  gn_partial<<<512, 256, 0, stream>>>(x, part);
  gn_finish<<<1, 64, 0, stream>>>(part, stats);
  gn_apply<<<dim3(32, 16, 8), dim3(32, 8), 0, stream>>>(x, stats, gn_w, gn_b, xn);
  cvt_w<<<1024, 256, 0, stream>>>((const float4*)wq, (const float4*)wk,
                                  (const float4*)wv, (const float4*)wp,
                                  bq, bk, wqkb, wvb, wpb, bqk);
  gemm_nt<<<dim3(64, 8), 256, 0, stream>>>(xn, wqkb, bqk, qkb, 8192, 1024, 512);
  gemm_tn2<<<dim3(128, 4), 256, 0, stream>>>(wvb, xn, bv, nullptr, vTb, 8192, 512, 0);
  attn_fwd<<<dim3(8, 64), 512, 0, stream>>>(qkb, vTb, attno);
  gemm_tn2<<<dim3(128, 4), 256, 0, stream>>>(wpb, attno, bp, x, d_out, 8192, 512, 1);
}